// Round 5
// baseline (371.381 us; speedup 1.0000x reference)
//
#include <hip/hip_runtime.h>
#include <math.h>

#define NI 256
#define NJ 256
#define NK 1024
#define JCHUNK 32
#define KSEG 256            // per-wave k segment
#define HALO 16             // LDS halo floats on each side of the segment
#define WREG 304            // floats per wave region (288 used, padded)
#define FLT_MAX_ 3.402823466e+38f

typedef float float4v __attribute__((ext_vector_type(4)));

__device__ __forceinline__ float finalize(float n, float d) {
    // rcp is ~1 ulp; threshold is 1.56e-2 absolute. d==0,n==0 -> 0*inf=nan -> 1.0.
    float r = n * __builtin_amdgcn_rcpf(d);
    if (isnan(r)) r = 1.0f;
    else if (isinf(r)) r = (r > 0.f) ? FLT_MAX_ : -FLT_MAX_;
    return r;
}

// Sliding 20-window sums along k, all-aligned b128 reads.
// Quads Q0..Q6 cover floats [base-12, base+15] of the logical row.
//   w0 = f[base-10 .. base+9]  = Q0[2..3] + Q1+Q2+Q3+Q4 + Q5[0..1]
//   w_{e+1} = w_e + f[base+10+e] - f[base-10+e]
__device__ __forceinline__ void kwindow(const float* __restrict__ row, int base,
                                        float& w0, float& w1, float& w2, float& w3) {
    const float4v* p = (const float4v*)(row + HALO + base - 12);
    float4v q0 = p[0], q1 = p[1], q2 = p[2], q3 = p[3], q4 = p[4], q5 = p[5], q6 = p[6];
    float mid = (q1[0] + q1[1] + q1[2] + q1[3]) + (q2[0] + q2[1] + q2[2] + q2[3])
              + (q3[0] + q3[1] + q3[2] + q3[3]) + (q4[0] + q4[1] + q4[2] + q4[3]);
    w0 = q0[2] + q0[3] + mid + q5[0] + q5[1];
    w1 = w0 + q5[2] - q0[2];
    w2 = w1 + q5[3] - q0[3];
    w3 = w2 + q6[0] - q1[0];
}

__global__ __launch_bounds__(256, 8)
void semblance_kernel(const float* __restrict__ x, float* __restrict__ out) {
    // one private region per wave — no cross-wave sharing, no block barriers
    __shared__ __align__(16) float lds[4][2][WREG];

    const int tid  = threadIdx.x;
    const int lane = tid & 63;
    const int wave = tid >> 6;
    const int i    = blockIdx.y;
    const int j0   = blockIdx.x * JCHUNK;
    const int k0   = wave * KSEG;
    const int base = lane * 4;

    float* Wn = &lds[wave][0][0];
    float* Wd = &lds[wave][1][0];

    const float* xi = x + (size_t)i * NJ * NK;
    const float* xk = xi + k0 + base;

    // halo: lanes 0-3 -> left slots, lanes 4-7 -> right slots
    const bool hal   = (lane < 8);
    const int  hslot = (lane < 4) ? (4 * lane) : (KSEG + 4 * lane);
    const int  hk    = k0 - HALO + hslot;
    const bool hkok  = (hk >= 0) && (hk < NK);
    const float* xh  = xi + hk;

    // register ring: rows j-2..j+2 for j = j0
    float4v r0, r1, r2, r3, r4;
    r0 = (j0 - 2 >= 0) ? *(const float4v*)(xk + (size_t)(j0 - 2) * NK) : (float4v)0.f;
    r1 = (j0 - 1 >= 0) ? *(const float4v*)(xk + (size_t)(j0 - 1) * NK) : (float4v)0.f;
    r2 = *(const float4v*)(xk + (size_t)j0 * NK);
    r3 = (j0 + 1 < NJ) ? *(const float4v*)(xk + (size_t)(j0 + 1) * NK) : (float4v)0.f;
    r4 = (j0 + 2 < NJ) ? *(const float4v*)(xk + (size_t)(j0 + 2) * NK) : (float4v)0.f;

    #pragma unroll 2
    for (int jj = 0; jj < JCHUNK; ++jj) {
        const int j = j0 + jj;

        // halo lanes reload their 5 rows (L1-hot re-reads)
        float4v h0 = (float4v)0.f, h1 = (float4v)0.f, h2 = (float4v)0.f,
                h3 = (float4v)0.f, h4 = (float4v)0.f;
        if (hal && hkok) {
            if (j - 2 >= 0) h0 = *(const float4v*)(xh + (size_t)(j - 2) * NK);
            if (j - 1 >= 0) h1 = *(const float4v*)(xh + (size_t)(j - 1) * NK);
            h2 = *(const float4v*)(xh + (size_t)j * NK);
            if (j + 1 < NJ) h3 = *(const float4v*)(xh + (size_t)(j + 1) * NK);
            if (j + 2 < NJ) h4 = *(const float4v*)(xh + (size_t)(j + 2) * NK);
        }

        // prefetch next ring row early
        float4v nxt = (float4v)0.f;
        if (jj + 1 < JCHUNK && j + 3 < NJ)
            nxt = *(const float4v*)(xk + (size_t)(j + 3) * NK);

        // main j-window sums -> LDS
        float4v s = r0 + r1 + r2 + r3 + r4;
        float4v t = r0 * r0 + r1 * r1 + r2 * r2 + r3 * r3 + r4 * r4;
        *(float4v*)(&Wn[HALO + base]) = s * s;
        *(float4v*)(&Wd[HALO + base]) = t;

        if (hal) {
            float4v hs = h0 + h1 + h2 + h3 + h4;
            float4v ht = h0 * h0 + h1 * h1 + h2 * h2 + h3 * h3 + h4 * h4;
            *(float4v*)(&Wn[hslot]) = hs * hs;
            *(float4v*)(&Wd[hslot]) = ht;
        }

        // wave-internal write->read ordering (DS pipe in-order per wave)
        __builtin_amdgcn_wave_barrier();
        asm volatile("" ::: "memory");

        float wn0, wn1, wn2, wn3, wd0, wd1, wd2, wd3;
        kwindow(Wn, base, wn0, wn1, wn2, wn3);
        kwindow(Wd, base, wd0, wd1, wd2, wd3);

        const int jlo = (j - 2 < 0) ? 0 : j - 2;
        const int jhi = (j + 2 > NJ - 1) ? NJ - 1 : j + 2;
        const float norm = (float)(jhi - jlo + 1);

        float4v o;
        o[0] = finalize(wn0, wd0 * norm);
        o[1] = finalize(wn1, wd1 * norm);
        o[2] = finalize(wn2, wd2 * norm);
        o[3] = finalize(wn3, wd3 * norm);
        *(float4v*)(out + ((size_t)i * NJ + j) * NK + k0 + base) = o;

        r0 = r1; r1 = r2; r2 = r3; r3 = r4; r4 = nxt;

        __builtin_amdgcn_wave_barrier();
        asm volatile("" ::: "memory");
    }
}

extern "C" void kernel_launch(void* const* d_in, const int* in_sizes, int n_in,
                              void* d_out, int out_size, void* d_ws, size_t ws_size,
                              hipStream_t stream) {
    const float* x = (const float*)d_in[0];
    float* out = (float*)d_out;
    dim3 grid(NJ / JCHUNK, NI);   // (8, 256) = 2048 blocks = 8 blocks/CU
    semblance_kernel<<<grid, 256, 0, stream>>>(x, out);
}

// Round 6
// 120.868 us; speedup vs baseline: 3.0726x; 3.0726x over previous
//
#include <hip/hip_runtime.h>
#include <math.h>

#define NI 256
#define NJ 256
#define NK 1024
#define JCHUNK 32
#define HALO 16
#define LROW (HALO + NK + HALO)   // 1056 floats
#define FLT_MAX_ 3.402823466e+38f

typedef float float4v __attribute__((ext_vector_type(4)));

__device__ __forceinline__ float finalize(float n, float d) {
    // rcp is ~1 ulp; threshold is 1.56e-2 absolute. 0/0 -> 0*inf = nan -> 1.0.
    float r = n * __builtin_amdgcn_rcpf(d);
    if (isnan(r)) r = 1.0f;
    else if (isinf(r)) r = (r > 0.f) ? FLT_MAX_ : -FLT_MAX_;
    return r;
}

// Sliding 20-window sums along k, all-aligned b128 reads (conflict-free, R5).
// Quads Q0..Q6 cover floats [base-12, base+15].
//   w0 = f[base-10 .. base+9]  = Q0[2..3] + Q1+Q2+Q3+Q4 + Q5[0..1]
//   w_{e+1} = w_e + f[base+10+e] - f[base-10+e]
__device__ __forceinline__ void kwindow(const float* __restrict__ row, int base,
                                        float& w0, float& w1, float& w2, float& w3) {
    const float4v* p = (const float4v*)(row + HALO + base - 12);
    float4v q0 = p[0], q1 = p[1], q2 = p[2], q3 = p[3], q4 = p[4], q5 = p[5], q6 = p[6];
    float mid = (q1[0] + q1[1] + q1[2] + q1[3]) + (q2[0] + q2[1] + q2[2] + q2[3])
              + (q3[0] + q3[1] + q3[2] + q3[3]) + (q4[0] + q4[1] + q4[2] + q4[3]);
    w0 = q0[2] + q0[3] + mid + q5[0] + q5[1];
    w1 = w0 + q5[2] - q0[2];
    w2 = w1 + q5[3] - q0[3];
    w3 = w2 + q6[0] - q1[0];
}

__global__ __launch_bounds__(256)
void semblance_kernel(const float* __restrict__ x, float* __restrict__ out) {
    // block-shared, double-buffered s1^2 and sum(x^2) rows with static zero pads
    __shared__ __align__(16) float s_num[2][LROW];
    __shared__ __align__(16) float s_den[2][LROW];

    const int tid  = threadIdx.x;
    const int i    = blockIdx.y;
    const int j0   = blockIdx.x * JCHUNK;
    const int base = tid * 4;          // this thread's first k (0..1020)

    // zero the pads ONCE — x is zero outside [0,NK), so these never change
    if (tid < HALO) {
        s_num[0][tid] = 0.f; s_den[0][tid] = 0.f;
        s_num[1][tid] = 0.f; s_den[1][tid] = 0.f;
        s_num[0][HALO + NK + tid] = 0.f; s_den[0][HALO + NK + tid] = 0.f;
        s_num[1][HALO + NK + tid] = 0.f; s_den[1][HALO + NK + tid] = 0.f;
    }

    const float* xk = x + (size_t)i * NJ * NK + base;

    // register ring: rows j-2..j+2 for j = j0
    float4v r0, r1, r2, r3, r4;
    r0 = (j0 - 2 >= 0) ? *(const float4v*)(xk + (size_t)(j0 - 2) * NK) : (float4v)0.f;
    r1 = (j0 - 1 >= 0) ? *(const float4v*)(xk + (size_t)(j0 - 1) * NK) : (float4v)0.f;
    r2 = *(const float4v*)(xk + (size_t)j0 * NK);
    r3 = (j0 + 1 < NJ) ? *(const float4v*)(xk + (size_t)(j0 + 1) * NK) : (float4v)0.f;
    r4 = (j0 + 2 < NJ) ? *(const float4v*)(xk + (size_t)(j0 + 2) * NK) : (float4v)0.f;

    #pragma unroll 2
    for (int jj = 0; jj < JCHUNK; ++jj) {
        const int j = j0 + jj;
        const int b = jj & 1;

        // j-window sums from the register ring
        float4v s = r0 + r1 + r2 + r3 + r4;
        float4v t = r0 * r0 + r1 * r1 + r2 * r2 + r3 * r3 + r4 * r4;
        *(float4v*)(&s_num[b][HALO + base]) = s * s;
        *(float4v*)(&s_den[b][HALO + base]) = t;

        // prefetch next ring row; latency hides under barrier + k-phase
        float4v nxt = (float4v)0.f;
        if (jj + 1 < JCHUNK && j + 3 < NJ)
            nxt = *(const float4v*)(xk + (size_t)(j + 3) * NK);

        __syncthreads();

        float wn0, wn1, wn2, wn3, wd0, wd1, wd2, wd3;
        kwindow(s_num[b], base, wn0, wn1, wn2, wn3);
        kwindow(s_den[b], base, wd0, wd1, wd2, wd3);

        const int jlo = (j - 2 < 0) ? 0 : j - 2;
        const int jhi = (j + 2 > NJ - 1) ? NJ - 1 : j + 2;
        const float norm = (float)(jhi - jlo + 1);

        float4v o;
        o[0] = finalize(wn0, wd0 * norm);
        o[1] = finalize(wn1, wd1 * norm);
        o[2] = finalize(wn2, wd2 * norm);
        o[3] = finalize(wn3, wd3 * norm);
        *(float4v*)(out + ((size_t)i * NJ + j) * NK + base) = o;

        // slide the ring (static names, unroll keeps these as renames)
        r0 = r1; r1 = r2; r2 = r3; r3 = r4; r4 = nxt;
        // single barrier per iteration: next iter writes the OTHER buffer;
        // its barrier orders those writes after all reads of this buffer
    }
}

extern "C" void kernel_launch(void* const* d_in, const int* in_sizes, int n_in,
                              void* d_out, int out_size, void* d_ws, size_t ws_size,
                              hipStream_t stream) {
    const float* x = (const float*)d_in[0];
    float* out = (float*)d_out;
    dim3 grid(NJ / JCHUNK, NI);   // (8, 256) = 2048 blocks
    semblance_kernel<<<grid, 256, 0, stream>>>(x, out);
}